// Round 11
// baseline (1159.110 us; speedup 1.0000x reference)
//
#include <hip/hip_runtime.h>

#define Bn 256
#define Tn 512
#define Vn 64
#define Hn 256
#define INn 129
#define Cc 8                 // timesteps per chunk (fallback path)
#define NCH (Tn / Cc)
#define WU 68                // packed uints per W_ih row (136 f16 cols)
#define WSZ (768 * WU)       // uints for packed W_ih
#define GX_OFF (262144)      // byte offset of gx in ws
#define GX_BYTES ((size_t)Bn * Tn * 768 * 2)
#define AST 168              // A-tile LDS stride in halves (staging)
#define CST 264              // C-tile LDS stride in halves (epilogue transpose)

typedef __fp16 half2_t __attribute__((ext_vector_type(2)));
typedef __fp16 half8_t __attribute__((ext_vector_type(8)));
typedef float f32x4 __attribute__((ext_vector_type(4)));

static __device__ __forceinline__ unsigned int cvt2(float a, float b) {
  return __builtin_bit_cast(unsigned int, __builtin_amdgcn_cvt_pkrtz(a, b));
}

// builtin dot2 — compiler-modeled (hazards known). NEVER use inline-asm ops in a stream
// containing MFMAs: R3/R5/R6 (asm dot2 + MFMA) and R7 (asm MFMA) failed correctness;
// builtin-only kernels pass (R0/R1/R4/R8/R9 — R9 is the controlled A/B that proved it).
static __device__ __forceinline__ float dot2(unsigned int w, unsigned int x, float acc) {
#if __has_builtin(__builtin_amdgcn_fdot2)
  return __builtin_amdgcn_fdot2(__builtin_bit_cast(half2_t, w),
                                __builtin_bit_cast(half2_t, x), acc, false);
#else
  half2_t a = __builtin_bit_cast(half2_t, w);
  half2_t b = __builtin_bit_cast(half2_t, x);
  return acc + (float)a.x * (float)b.x + (float)a.y * (float)b.y;
#endif
}

// pair-sum across lanes 2i<->2i+1 (DPP quad_perm [1,0,3,2]) — builtin, R0-proven
static __device__ __forceinline__ float pair_sum(float v) {
#if __has_builtin(__builtin_amdgcn_update_dpp)
  int x = __builtin_amdgcn_update_dpp(0, __builtin_bit_cast(int, v), 0xB1, 0xF, 0xF, true);
  return v + __builtin_bit_cast(float, x);
#else
  int j = __builtin_amdgcn_ds_swizzle(__builtin_bit_cast(int, v), 0x041F);
  return v + __builtin_bit_cast(float, j);
#endif
}

static __device__ __forceinline__ float fast_exp2(float x) {
#if __has_builtin(__builtin_amdgcn_exp2f)
  return __builtin_amdgcn_exp2f(x);
#else
  return exp2f(x);
#endif
}
static __device__ __forceinline__ float fast_rcp(float x) {
#if __has_builtin(__builtin_amdgcn_rcpf)
  return __builtin_amdgcn_rcpf(x);
#else
  return 1.f / x;
#endif
}
static __device__ __forceinline__ float sigmoid_f(float x) {
  return fast_rcp(1.f + fast_exp2(-1.44269504f * x));
}
static __device__ __forceinline__ float tanh_f(float x) {
  return 1.f - 2.f * fast_rcp(1.f + fast_exp2(2.88539008f * x));
}
static __device__ __forceinline__ float h2f(unsigned short u) {
  return (float)__builtin_bit_cast(__fp16, u);
}

// Pack W_ih (768x129 f32) into [768][68] f16-pair uints in workspace (cols >=129 zero).
__global__ void convert_wih(const float* __restrict__ W_ih, unsigned int* __restrict__ w16) {
  int idx = blockIdx.x * 256 + threadIdx.x;
  if (idx >= WSZ) return;
  int j = idx / WU, c = idx - j * WU;
  int col = 2 * c;
  float f0 = (col < INn) ? W_ih[(size_t)j * INn + col] : 0.f;
  float f1 = (col + 1 < INn) ? W_ih[(size_t)j * INn + col + 1] : 0.f;
  w16[idx] = cvt2(f0, f1);
}

// ---------------- GEMM v2 (R8-proven): stage x once, loop n0 in-block --------------------
__global__ __launch_bounds__(256, 2)
void gx_gemm(const float* __restrict__ times_in, const float* __restrict__ data_in,
             const float* __restrict__ mask_in, const unsigned int* __restrict__ w16,
             const float* __restrict__ b_ih, const float* __restrict__ b_hh,
             __fp16* __restrict__ gx) {
  __shared__ __align__(16) __fp16 xa[64 * AST];
  __shared__ __align__(16) __fp16 ct[64 * CST];

  const int tid = threadIdx.x;
  const int bt = blockIdx.x;
  const int b = bt >> 3, tc = bt & 7;
  const int t0 = tc * 64;

  {
    int r = tid >> 2, s = tid & 3;
    const float* src = (s < 2)
        ? data_in + ((size_t)b * Tn + t0 + r) * Vn + s * 32
        : mask_in + ((size_t)b * Tn + t0 + r) * Vn + (s - 2) * 32;
    unsigned int* dst = (unsigned int*)(xa + r * AST) + s * 16;
#pragma unroll
    for (int i = 0; i < 8; ++i) {
      float4 v = ((const float4*)src)[i];
      dst[2 * i] = cvt2(v.x, v.y);
      dst[2 * i + 1] = cvt2(v.z, v.w);
    }
  }
  if (tid < 64) {
    int g = t0 + tid;
    float tcur = times_in[(size_t)b * Tn + g];
    float d = (g < Tn - 1) ? times_in[(size_t)b * Tn + g + 1] - tcur : 0.f;
    unsigned int* p = (unsigned int*)(xa + tid * AST + 128);
    p[0] = cvt2(d, 0.f);
#pragma unroll
    for (int i = 1; i < 20; ++i) p[i] = 0u;
  }
  __syncthreads();

  const int w = tid >> 6, lane = tid & 63;
  const int m = lane & 15, q = lane >> 4;

#pragma unroll 1
  for (int nb = 0; nb < 3; ++nb) {
    const int n0 = nb * 256;
    const int nw = n0 + w * 64;

    f32x4 acc[4][4];
#pragma unroll
    for (int i = 0; i < 4; ++i)
#pragma unroll
      for (int j = 0; j < 4; ++j) acc[i][j] = f32x4{0.f, 0.f, 0.f, 0.f};

#pragma unroll
    for (int kt = 0; kt < 5; ++kt) {
      const int k0 = kt * 32 + q * 8;
      half8_t bf[4], af[4];
#pragma unroll
      for (int nt = 0; nt < 4; ++nt) {
        int n = nw + nt * 16 + m;
        uint4 bv = *(const uint4*)(w16 + (size_t)n * WU + (k0 >> 1));
        bf[nt] = __builtin_bit_cast(half8_t, bv);
      }
#pragma unroll
      for (int mt = 0; mt < 4; ++mt) {
        uint4 av = *(const uint4*)(xa + (mt * 16 + m) * AST + k0);
        af[mt] = __builtin_bit_cast(half8_t, av);
      }
#pragma unroll
      for (int mt = 0; mt < 4; ++mt)
#pragma unroll
        for (int nt = 0; nt < 4; ++nt)
          acc[mt][nt] = __builtin_amdgcn_mfma_f32_16x16x32_f16(af[mt], bf[nt], acc[mt][nt], 0, 0, 0);
    }

    float bias[4];
#pragma unroll
    for (int nt = 0; nt < 4; ++nt) {
      int n = nw + nt * 16 + m;
      bias[nt] = b_ih[n] + ((n < 512) ? b_hh[n] : 0.f);  // fold r,z hh-biases
    }

#pragma unroll
    for (int mt = 0; mt < 4; ++mt)
#pragma unroll
      for (int nt = 0; nt < 4; ++nt)
#pragma unroll
        for (int r = 0; r < 4; ++r)
          ct[(mt * 16 + q * 4 + r) * CST + w * 64 + nt * 16 + m] =
              (__fp16)(acc[mt][nt][r] + bias[nt]);
    __syncthreads();

    {
      const int tt = tid >> 2, qq = tid & 3;
      const uint4* src = (const uint4*)(ct + tt * CST) + qq * 8;
      uint4* dst = (uint4*)(gx + ((size_t)b * Tn + t0 + tt) * 768 + n0) + qq * 8;
#pragma unroll
      for (int i = 0; i < 8; ++i) dst[i] = src[i];
    }
    __syncthreads();  // protect ct before next n0 overwrites it
  }
}

// ---------------- Scan v17b: R9 hybrid + fine MFMA/dot2 interleave (sched_group_barrier) --
// R10 submission never ran (infra failure) — resubmit. R9 PASSED (hybrid correct with
// builtin fdot2) but step = 3800 cyc: MFMA ISSUE blocks on the busy matrix pipe (~1242 cyc
// to issue 32 MFMAs at 2 waves/SIMD), so the dot2 block, placed after the burst in program
// order, ran serially AFTER the drain. v17: per kc, {4 MFMA + 8 dot2 + next-iter ds_read}
// interleaved in program order and pinned with sched_group_barrier (compile-time directive,
// emits no instructions — correctness-safe per R9's A/B). After each MFMA the wave's next
// instrs are VALU dot2s, issuing on the free VALU pipe while the matrix pipe drains.
// v17b delta vs v17: DS_READ group directive only for kc<7 (kc=7 issues no ds_read; don't
// demand an impossible schedule). Everything outside the kc-loop is R9-verbatim (passing).
__global__ __launch_bounds__(512, 1)
void gru_scan_h5(const float* __restrict__ times_in, const float* __restrict__ W_hh,
                 const float* __restrict__ b_hh, const __fp16* __restrict__ gx,
                 float* __restrict__ out) {
  __shared__ __align__(16) __fp16 hl[2 * Hn];
  __shared__ short act[Tn];
  __shared__ int wave_cnt[8];
  __shared__ int nact_s;

  const int tid = threadIdx.x;
  const int b = blockIdx.x;
  const int lane = tid & 63;
  const int w = tid >> 6;   // wave id (MFMA mapping: wave owns r,z dims [w*32, w*32+32))
  const int m = lane & 15;  // MFMA tile column
  const int q = lane >> 4;  // MFMA k sub-offset group
  const int jg = tid >> 1;  // R0 mapping: this thread-pair's h-dim (= w*32 + (lane>>1))
  const int ks = tid & 1;   // R0 mapping: K-half for the n-gate dot2

  // ---- compact active timesteps (R0/R1 verbatim) ----
  {
    float tv = times_in[(size_t)b * Tn + tid];
    bool on = tv > 0.f;
    unsigned long long mask = __ballot(on);
    int within = __popcll(mask & ((1ull << lane) - 1ull));
    if (lane == 0) wave_cnt[w] = __popcll(mask);
    __syncthreads();
    int off = 0;
#pragma unroll
    for (int i = 0; i < 8; ++i) off += (i < w) ? wave_cnt[i] : 0;
    if (on) act[off + within] = (short)tid;
    if (tid == 0) {
      int n = 0;
#pragma unroll
      for (int i = 0; i < 8; ++i) n += wave_cnt[i];
      nact_s = n;
    }
  }

  // ---- W_hh(r,z) -> register-resident B-fragments (R1 verbatim, tiles 0..3) ----
  // wb[g*2+hf][kc]: lane holds W_hh[g*256 + w*32 + hf*16 + m][kc*32 + q*8 + j], j=0..7
  half8_t wb[4][8];
#pragma unroll
  for (int g = 0; g < 2; ++g)
#pragma unroll
    for (int hf = 0; hf < 2; ++hf) {
      const float* wr = W_hh + (size_t)(g * 256 + w * 32 + hf * 16 + m) * Hn;
#pragma unroll
      for (int kc = 0; kc < 8; ++kc) {
        const float4 a = *(const float4*)(wr + kc * 32 + q * 8);
        const float4 c = *(const float4*)(wr + kc * 32 + q * 8 + 4);
        uint4 u;
        u.x = cvt2(a.x, a.y);
        u.y = cvt2(a.z, a.w);
        u.z = cvt2(c.x, c.y);
        u.w = cvt2(c.z, c.w);
        wb[g * 2 + hf][kc] = __builtin_bit_cast(half8_t, u);
      }
    }

  // ---- W_hn row-half for dim jg (R0 verbatim): K-half ks, 64 f16 pairs ----
  unsigned int whn[64];
  {
    const float* w2 = W_hh + (size_t)(jg + 512) * Hn + ks * 128;
#pragma unroll
    for (int c = 0; c < 64; ++c) whn[c] = cvt2(w2[2 * c], w2[2 * c + 1]);
  }
  const float bhn = b_hh[jg + 512];  // r,z hh-biases folded into gx by the GEMM

  hl[tid] = (__fp16)0.f;  // both ping-pong buffers
  __syncthreads();

  const int nact = nact_s;
  const __fp16* gxb = gx + (size_t)b * Tn * 768;
  float hcur = 0.f;
  int cur = 0;

  if (nact > 0) {
    int t0i = act[0];
    float gr = (float)gxb[(size_t)t0i * 768 + jg];
    float gz = (float)gxb[(size_t)t0i * 768 + 256 + jg];
    float gn = (float)gxb[(size_t)t0i * 768 + 512 + jg];

#pragma unroll 1
    for (int i = 0; i < nact; ++i) {
      // prefetch next active step's gx (clamped; last-iter values unused)
      const int ni = (i + 1 < nact) ? (i + 1) : (nact - 1);
      const int tnx = act[ni];
      const __fp16* p = gxb + (size_t)tnx * 768;
      __fp16 pr = p[jg], pz = p[256 + jg], pn = p[512 + jg];

      // ---- A-frag prefetch (R9 verbatim): h broadcast into all 16 A-rows ----
      const uint4* ha = (const uint4*)(hl + cur * Hn);
      uint4 afu[8];
#pragma unroll
      for (int kc = 0; kc < 8; ++kc) afu[kc] = ha[kc * 4 + q];

      // dot2 h-source, software-pipelined one kc ahead (LDS latency cover)
      const uint4* hb = (const uint4*)(hl + cur * Hn) + ks * 16;
      uint4 hv0 = hb[0], hv1 = hb[1];

      f32x4 aR0 = f32x4{0.f, 0.f, 0.f, 0.f};
      f32x4 aR1 = f32x4{0.f, 0.f, 0.f, 0.f};
      f32x4 aZ0 = f32x4{0.f, 0.f, 0.f, 0.f};
      f32x4 aZ1 = f32x4{0.f, 0.f, 0.f, 0.f};
      float s0 = 0.f, s1 = 0.f, s2 = 0.f, s3 = 0.f;

#pragma unroll
      for (int kc = 0; kc < 8; ++kc) {
        half8_t a = __builtin_bit_cast(half8_t, afu[kc]);
        uint4 nx0 = hv0, nx1 = hv1;
        if (kc < 7) {
          nx0 = hb[2 * kc + 2];
          nx1 = hb[2 * kc + 3];
        }
        aR0 = __builtin_amdgcn_mfma_f32_16x16x32_f16(a, wb[0][kc], aR0, 0, 0, 0);
        aR1 = __builtin_amdgcn_mfma_f32_16x16x32_f16(a, wb[1][kc], aR1, 0, 0, 0);
        aZ0 = __builtin_amdgcn_mfma_f32_16x16x32_f16(a, wb[2][kc], aZ0, 0, 0, 0);
        aZ1 = __builtin_amdgcn_mfma_f32_16x16x32_f16(a, wb[3][kc], aZ1, 0, 0, 0);
        s0 = dot2(whn[8 * kc + 0], hv0.x, s0);
        s1 = dot2(whn[8 * kc + 1], hv0.y, s1);
        s2 = dot2(whn[8 * kc + 2], hv0.z, s2);
        s3 = dot2(whn[8 * kc + 3], hv0.w, s3);
        s0 = dot2(whn[8 * kc + 4], hv1.x, s0);
        s1 = dot2(whn[8 * kc + 5], hv1.y, s1);
        s2 = dot2(whn[8 * kc + 6], hv1.z, s2);
        s3 = dot2(whn[8 * kc + 7], hv1.w, s3);
        hv0 = nx0;
        hv1 = nx1;
        // pin the 1-MFMA : 2-dot2 interleave (compile-time only, no instructions)
        __builtin_amdgcn_sched_group_barrier(0x008, 1, 0);  // MFMA
        __builtin_amdgcn_sched_group_barrier(0x002, 2, 0);  // VALU (dot2 x2)
        __builtin_amdgcn_sched_group_barrier(0x008, 1, 0);
        __builtin_amdgcn_sched_group_barrier(0x002, 2, 0);
        __builtin_amdgcn_sched_group_barrier(0x008, 1, 0);
        __builtin_amdgcn_sched_group_barrier(0x002, 2, 0);
        __builtin_amdgcn_sched_group_barrier(0x008, 1, 0);
        __builtin_amdgcn_sched_group_barrier(0x002, 2, 0);
        if (kc < 7) {
          __builtin_amdgcn_sched_group_barrier(0x100, 2, 0);  // DS_READ (next hv pair)
        }
      }

      float shn = pair_sum((s0 + s1) + (s2 + s3));  // sum K-halves across thread pair

      // ---- glue: gather r,z pre-activations into the jg mapping (R9 verbatim) ----
      const int src = (lane >> 1) & 15;  // = jg & 15, donor lane in q=0 group
      float r0v = __shfl(aR0[0], src, 64);
      float r1v = __shfl(aR1[0], src, 64);
      float z0v = __shfl(aZ0[0], src, 64);
      float z1v = __shfl(aZ1[0], src, 64);
      float rp = (lane & 32) ? r1v : r0v;
      float zp = (lane & 32) ? z1v : z0v;

      // ---- tail (R0 verbatim) ----
      float r = sigmoid_f(gr + rp);
      float z = sigmoid_f(gz + zp);
      float n = tanh_f(gn + r * (shn + bhn));
      hcur = (1.f - z) * n + z * hcur;

      if (ks == 0) hl[(cur ^ 1) * Hn + jg] = (__fp16)hcur;
      // raw barrier (R1/R4/R8/R9-proven): drain LDS only, keep gx loads in flight
      asm volatile("s_waitcnt lgkmcnt(0)" ::: "memory");
      __builtin_amdgcn_s_barrier();
      __builtin_amdgcn_sched_barrier(0);
      cur ^= 1;

      gr = (float)pr; gz = (float)pz; gn = (float)pn;
    }
  }

  if (ks == 0) out[(size_t)b * Hn + jg] = hcur;
}

// ---------------- Fallback (R3): in-kernel phase A, used only if ws too small -------------
template <bool USE_WS>
static __device__ __forceinline__ void phaseA_pass(int col, const unsigned int* __restrict__ w16,
                                                   const float* __restrict__ W_ih,
                                                   const unsigned int* x_lds, float* a) {
  const uint4* wp = (const uint4*)(w16) + (size_t)col * (WU / 4);
  const float* wf = W_ih + (size_t)col * INn;
#pragma unroll 2
  for (int kp = 0; kp < 8; ++kp) {
    uint4 wa, wb;
    if constexpr (USE_WS) {
      wa = wp[2 * kp];
      wb = wp[2 * kp + 1];
    } else {
      const float* f = wf + 16 * kp;
      wa.x = cvt2(f[0], f[1]);   wa.y = cvt2(f[2], f[3]);
      wa.z = cvt2(f[4], f[5]);   wa.w = cvt2(f[6], f[7]);
      wb.x = cvt2(f[8], f[9]);   wb.y = cvt2(f[10], f[11]);
      wb.z = cvt2(f[12], f[13]); wb.w = cvt2(f[14], f[15]);
    }
#pragma unroll
    for (int t = 0; t < Cc; ++t) {
      const uint4* xp = (const uint4*)&x_lds[t * WU + kp * 8];
      uint4 xa = xp[0], xb = xp[1];
      a[t] = dot2(wa.x, xa.x, a[t]);
      a[t] = dot2(wa.y, xa.y, a[t]);
      a[t] = dot2(wa.z, xa.z, a[t]);
      a[t] = dot2(wa.w, xa.w, a[t]);
      a[t] = dot2(wb.x, xb.x, a[t]);
      a[t] = dot2(wb.y, xb.y, a[t]);
      a[t] = dot2(wb.z, xb.z, a[t]);
      a[t] = dot2(wb.w, xb.w, a[t]);
    }
  }
  uint4 wt;
  if constexpr (USE_WS) {
    wt = wp[16];
  } else {
    wt.x = cvt2(wf[128], 0.f); wt.y = 0u; wt.z = 0u; wt.w = 0u;
  }
#pragma unroll
  for (int t = 0; t < Cc; ++t) {
    uint4 xt = *(const uint4*)&x_lds[t * WU + 64];
    a[t] = dot2(wt.x, xt.x, a[t]);
    a[t] = dot2(wt.y, xt.y, a[t]);
  }
}

template <bool USE_WS>
__global__ __launch_bounds__(512, 2)
void gru_scan_fb(const float* __restrict__ times_in, const float* __restrict__ data_in,
                 const float* __restrict__ mask_in, const unsigned int* __restrict__ w16,
                 const float* __restrict__ W_ih, const float* __restrict__ W_hh,
                 const float* __restrict__ b_ih, const float* __restrict__ b_hh,
                 float* __restrict__ out) {
  __shared__ __align__(16) float gx_lds[Cc * 768];
  __shared__ __align__(16) unsigned int x_lds[Cc * WU];
  __shared__ __align__(16) __fp16 h_buf[2 * Hn];
  __shared__ __align__(16) float t_lds[Tn];

  const int tid = threadIdx.x;
  const int b = blockIdx.x;
  const int jg = tid >> 1;
  const int ks = tid & 1;

  t_lds[tid] = times_in[(size_t)b * Tn + tid];

  unsigned int whr[64], whz[64], whn[64];
  {
    const float* w0 = W_hh + (size_t)jg * Hn + ks * 128;
    const float* w1 = W_hh + (size_t)(jg + 256) * Hn + ks * 128;
    const float* w2 = W_hh + (size_t)(jg + 512) * Hn + ks * 128;
#pragma unroll
    for (int c = 0; c < 64; ++c) {
      whr[c] = cvt2(w0[2 * c], w0[2 * c + 1]);
      whz[c] = cvt2(w1[2 * c], w1[2 * c + 1]);
      whn[c] = cvt2(w2[2 * c], w2[2 * c + 1]);
    }
  }
  const float brh = b_hh[jg];
  const float bzh = b_hh[jg + 256];
  const float bhn = b_hh[jg + 512];
  const float bi1 = b_ih[tid];
  const float bi2 = (tid < 256) ? b_ih[512 + tid] : 0.f;

  h_buf[tid] = (__fp16)0.f;
  __syncthreads();

  float hcur = 0.f;
  int cur = 0;
#pragma unroll 1
  for (int ch = 0; ch < NCH; ++ch) {
    const int t0 = ch * Cc;
    {
      int t = tid >> 6;
      int c = tid & 63;
      const float* src = (c < 32)
          ? data_in + ((size_t)b * Tn + t0 + t) * Vn + 2 * c
          : mask_in + ((size_t)b * Tn + t0 + t) * Vn + 2 * (c - 32);
      float2 v = *(const float2*)src;
      x_lds[t * WU + c] = cvt2(v.x, v.y);
      if (tid < Cc) {
        int g = t0 + tid;
        float d = (g < Tn - 1) ? (t_lds[g + 1] - t_lds[g]) : 0.f;
        uint4 tl;
        tl.x = cvt2(d, 0.f); tl.y = 0u; tl.z = 0u; tl.w = 0u;
        *(uint4*)&x_lds[tid * WU + 64] = tl;
      }
    }
    __syncthreads();
    {
      float a[Cc];
#pragma unroll
      for (int t = 0; t < Cc; ++t) a[t] = bi1;
      phaseA_pass<USE_WS>(tid, w16, W_ih, x_lds, a);
#pragma unroll
      for (int t = 0; t < Cc; ++t) gx_lds[t * 768 + tid] = a[t];
      if (tid < 256) {
#pragma unroll
        for (int t = 0; t < Cc; ++t) a[t] = bi2;
        phaseA_pass<USE_WS>(512 + tid, w16, W_ih, x_lds, a);
#pragma unroll
        for (int t = 0; t < Cc; ++t) gx_lds[t * 768 + 512 + tid] = a[t];
      }
    }
    __syncthreads();
    for (int tt = 0; tt < Cc; ++tt) {
      float sr = 0.f, sz = 0.f, shn = 0.f;
      const uint4* hb = (const uint4*)(h_buf + cur * Hn + ks * 128);
#pragma unroll
      for (int c = 0; c < 16; ++c) {
        uint4 hv = hb[c];
        sr = dot2(whr[4 * c + 0], hv.x, sr);
        sz = dot2(whz[4 * c + 0], hv.x, sz);
        shn = dot2(whn[4 * c + 0], hv.x, shn);
        sr = dot2(whr[4 * c + 1], hv.y, sr);
        sz = dot2(whz[4 * c + 1], hv.y, sz);
        shn = dot2(whn[4 * c + 1], hv.y, shn);
        sr = dot2(whr[4 * c + 2], hv.z, sr);
        sz = dot2(whz[4 * c + 2], hv.z, sz);
        shn = dot2(whn[4 * c + 2], hv.z, shn);
        sr = dot2(whr[4 * c + 3], hv.w, sr);
        sz = dot2(whz[4 * c + 3], hv.w, sz);
        shn = dot2(whn[4 * c + 3], hv.w, shn);
      }
      float gxr = gx_lds[tt * 768 + jg];
      float gxz = gx_lds[tt * 768 + 256 + jg];
      float gxn = gx_lds[tt * 768 + 512 + jg];
      sr = pair_sum(sr);
      sz = pair_sum(sz);
      shn = pair_sum(shn);
      float r = sigmoid_f(gxr + sr + brh);
      float z = sigmoid_f(gxz + sz + bzh);
      float n = tanh_f(gxn + r * (shn + bhn));
      float hN = (1.f - z) * n + z * hcur;
      hcur = (t_lds[t0 + tt] > 0.f) ? hN : hcur;
      if (ks == 0) h_buf[(cur ^ 1) * Hn + jg] = (__fp16)hcur;
      __syncthreads();
      cur ^= 1;
    }
  }
  if (ks == 0) out[(size_t)b * Hn + jg] = hcur;
}

extern "C" void kernel_launch(void* const* d_in, const int* in_sizes, int n_in,
                              void* d_out, int out_size, void* d_ws, size_t ws_size,
                              hipStream_t stream) {
  const float* times_in = (const float*)d_in[0];
  const float* data_in = (const float*)d_in[1];
  const float* mask_in = (const float*)d_in[2];
  const float* W_ih = (const float*)d_in[3];
  const float* W_hh = (const float*)d_in[4];
  const float* b_ih = (const float*)d_in[5];
  const float* b_hh = (const float*)d_in[6];
  float* out = (float*)d_out;

  unsigned int* w16 = (unsigned int*)d_ws;
  __fp16* gx = (__fp16*)((char*)d_ws + GX_OFF);

  if (ws_size >= GX_OFF + GX_BYTES) {
    hipLaunchKernelGGL(convert_wih, dim3((WSZ + 255) / 256), dim3(256), 0, stream, W_ih, w16);
    hipLaunchKernelGGL(gx_gemm, dim3(2048), dim3(256), 0, stream,
                       times_in, data_in, mask_in, w16, b_ih, b_hh, gx);
    hipLaunchKernelGGL(gru_scan_h5, dim3(Bn), dim3(512), 0, stream,
                       times_in, W_hh, b_hh, gx, out);
  } else if (ws_size >= (size_t)WSZ * 4) {
    hipLaunchKernelGGL(convert_wih, dim3((WSZ + 255) / 256), dim3(256), 0, stream, W_ih, w16);
    hipLaunchKernelGGL((gru_scan_fb<true>), dim3(Bn), dim3(512), 0, stream,
                       times_in, data_in, mask_in, w16, W_ih, W_hh, b_ih, b_hh, out);
  } else {
    hipLaunchKernelGGL((gru_scan_fb<false>), dim3(Bn), dim3(512), 0, stream,
                       times_in, data_in, mask_in, (const unsigned int*)nullptr, W_ih, W_hh,
                       b_ih, b_hh, out);
  }
}

// Round 12
// 703.561 us; speedup vs baseline: 1.6475x; 1.6475x over previous
//
#include <hip/hip_runtime.h>

#define Bn 256
#define Tn 512
#define Vn 64
#define Hn 256
#define INn 129
#define Cc 8                 // timesteps per chunk (fallback path)
#define NCH (Tn / Cc)
#define WU 68                // packed uints per W_ih row (136 f16 cols)
#define WSZ (768 * WU)       // uints for packed W_ih
#define GX_OFF (262144)      // byte offset of gx in ws
#define GX_BYTES ((size_t)Bn * Tn * 768 * 2)
#define AST 168              // A-tile LDS stride in halves (staging)
#define CST 264              // C-tile LDS stride in halves (epilogue transpose)

typedef __fp16 half2_t __attribute__((ext_vector_type(2)));
typedef __fp16 half8_t __attribute__((ext_vector_type(8)));
typedef float f32x4 __attribute__((ext_vector_type(4)));

static __device__ __forceinline__ unsigned int cvt2(float a, float b) {
  return __builtin_bit_cast(unsigned int, __builtin_amdgcn_cvt_pkrtz(a, b));
}

// builtin dot2 — compiler-modeled (hazards known). NEVER use inline-asm ops in a stream
// containing MFMAs: R3/R5/R6 (asm dot2 + MFMA) and R7 (asm MFMA) failed correctness;
// builtin-only kernels pass (R0/R1/R4/R8/R9 — R9 is the controlled A/B that proved it).
static __device__ __forceinline__ float dot2(unsigned int w, unsigned int x, float acc) {
#if __has_builtin(__builtin_amdgcn_fdot2)
  return __builtin_amdgcn_fdot2(__builtin_bit_cast(half2_t, w),
                                __builtin_bit_cast(half2_t, x), acc, false);
#else
  half2_t a = __builtin_bit_cast(half2_t, w);
  half2_t b = __builtin_bit_cast(half2_t, x);
  return acc + (float)a.x * (float)b.x + (float)a.y * (float)b.y;
#endif
}

// pair-sum across lanes 2i<->2i+1 (DPP quad_perm [1,0,3,2]) — fallback path
static __device__ __forceinline__ float pair_sum(float v) {
#if __has_builtin(__builtin_amdgcn_update_dpp)
  int x = __builtin_amdgcn_update_dpp(0, __builtin_bit_cast(int, v), 0xB1, 0xF, 0xF, true);
  return v + __builtin_bit_cast(float, x);
#else
  int j = __builtin_amdgcn_ds_swizzle(__builtin_bit_cast(int, v), 0x041F);
  return v + __builtin_bit_cast(float, j);
#endif
}

static __device__ __forceinline__ float fast_exp2(float x) {
#if __has_builtin(__builtin_amdgcn_exp2f)
  return __builtin_amdgcn_exp2f(x);
#else
  return exp2f(x);
#endif
}
static __device__ __forceinline__ float fast_rcp(float x) {
#if __has_builtin(__builtin_amdgcn_rcpf)
  return __builtin_amdgcn_rcpf(x);
#else
  return 1.f / x;
#endif
}
static __device__ __forceinline__ float sigmoid_f(float x) {
  return fast_rcp(1.f + fast_exp2(-1.44269504f * x));
}
static __device__ __forceinline__ float tanh_f(float x) {
  return 1.f - 2.f * fast_rcp(1.f + fast_exp2(2.88539008f * x));
}
static __device__ __forceinline__ float h2f(unsigned short u) {
  return (float)__builtin_bit_cast(__fp16, u);
}

// Pack W_ih (768x129 f32) into [768][68] f16-pair uints in workspace (cols >=129 zero).
__global__ void convert_wih(const float* __restrict__ W_ih, unsigned int* __restrict__ w16) {
  int idx = blockIdx.x * 256 + threadIdx.x;
  if (idx >= WSZ) return;
  int j = idx / WU, c = idx - j * WU;
  int col = 2 * c;
  float f0 = (col < INn) ? W_ih[(size_t)j * INn + col] : 0.f;
  float f1 = (col + 1 < INn) ? W_ih[(size_t)j * INn + col + 1] : 0.f;
  w16[idx] = cvt2(f0, f1);
}

// ---------------- GEMM v2 (R8-proven): stage x once, loop n0 in-block --------------------
// v1 was grid (2048,3): each (b,tc) x-tile staged 3x and blocks were MFMA-light. v2: grid
// 2048, n0 loops in-block over {0,256,512} with SEPARATE LDS buffers (xa persistent, ct
// reused) -> x staged once, 3x MFMA density, ~68MB less input FETCH. 55KB LDS, 2 blocks/CU.
__global__ __launch_bounds__(256, 2)
void gx_gemm(const float* __restrict__ times_in, const float* __restrict__ data_in,
             const float* __restrict__ mask_in, const unsigned int* __restrict__ w16,
             const float* __restrict__ b_ih, const float* __restrict__ b_hh,
             __fp16* __restrict__ gx) {
  __shared__ __align__(16) __fp16 xa[64 * AST];
  __shared__ __align__(16) __fp16 ct[64 * CST];

  const int tid = threadIdx.x;
  const int bt = blockIdx.x;
  const int b = bt >> 3, tc = bt & 7;
  const int t0 = tc * 64;

  {
    int r = tid >> 2, s = tid & 3;
    const float* src = (s < 2)
        ? data_in + ((size_t)b * Tn + t0 + r) * Vn + s * 32
        : mask_in + ((size_t)b * Tn + t0 + r) * Vn + (s - 2) * 32;
    unsigned int* dst = (unsigned int*)(xa + r * AST) + s * 16;
#pragma unroll
    for (int i = 0; i < 8; ++i) {
      float4 v = ((const float4*)src)[i];
      dst[2 * i] = cvt2(v.x, v.y);
      dst[2 * i + 1] = cvt2(v.z, v.w);
    }
  }
  if (tid < 64) {
    int g = t0 + tid;
    float tcur = times_in[(size_t)b * Tn + g];
    float d = (g < Tn - 1) ? times_in[(size_t)b * Tn + g + 1] - tcur : 0.f;
    unsigned int* p = (unsigned int*)(xa + tid * AST + 128);
    p[0] = cvt2(d, 0.f);
#pragma unroll
    for (int i = 1; i < 20; ++i) p[i] = 0u;
  }
  __syncthreads();

  const int w = tid >> 6, lane = tid & 63;
  const int m = lane & 15, q = lane >> 4;

#pragma unroll 1
  for (int nb = 0; nb < 3; ++nb) {
    const int n0 = nb * 256;
    const int nw = n0 + w * 64;

    f32x4 acc[4][4];
#pragma unroll
    for (int i = 0; i < 4; ++i)
#pragma unroll
      for (int j = 0; j < 4; ++j) acc[i][j] = f32x4{0.f, 0.f, 0.f, 0.f};

#pragma unroll
    for (int kt = 0; kt < 5; ++kt) {
      const int k0 = kt * 32 + q * 8;
      half8_t bf[4], af[4];
#pragma unroll
      for (int nt = 0; nt < 4; ++nt) {
        int n = nw + nt * 16 + m;
        uint4 bv = *(const uint4*)(w16 + (size_t)n * WU + (k0 >> 1));
        bf[nt] = __builtin_bit_cast(half8_t, bv);
      }
#pragma unroll
      for (int mt = 0; mt < 4; ++mt) {
        uint4 av = *(const uint4*)(xa + (mt * 16 + m) * AST + k0);
        af[mt] = __builtin_bit_cast(half8_t, av);
      }
#pragma unroll
      for (int mt = 0; mt < 4; ++mt)
#pragma unroll
        for (int nt = 0; nt < 4; ++nt)
          acc[mt][nt] = __builtin_amdgcn_mfma_f32_16x16x32_f16(af[mt], bf[nt], acc[mt][nt], 0, 0, 0);
    }

    float bias[4];
#pragma unroll
    for (int nt = 0; nt < 4; ++nt) {
      int n = nw + nt * 16 + m;
      bias[nt] = b_ih[n] + ((n < 512) ? b_hh[n] : 0.f);  // fold r,z hh-biases
    }

#pragma unroll
    for (int mt = 0; mt < 4; ++mt)
#pragma unroll
      for (int nt = 0; nt < 4; ++nt)
#pragma unroll
        for (int r = 0; r < 4; ++r)
          ct[(mt * 16 + q * 4 + r) * CST + w * 64 + nt * 16 + m] =
              (__fp16)(acc[mt][nt][r] + bias[nt]);
    __syncthreads();

    {
      const int tt = tid >> 2, qq = tid & 3;
      const uint4* src = (const uint4*)(ct + tt * CST) + qq * 8;
      uint4* dst = (uint4*)(gx + ((size_t)b * Tn + t0 + tt) * 768 + n0) + qq * 8;
#pragma unroll
      for (int i = 0; i < 8; ++i) dst[i] = src[i];
    }
    __syncthreads();  // protect ct before next n0 overwrites it
  }
}

// per-step gx registers (f16 bit patterns; converted at use, 2 steps after issue)
struct G6 {
  unsigned short r0, r1, z0, z1, n0, n1;
};
static __device__ __forceinline__ G6 load_gx(const unsigned short* p) {
  G6 g;
  g.r0 = p[0];
  g.r1 = p[16];
  g.z0 = p[256];
  g.z1 = p[272];
  g.n0 = p[512];
  g.n1 = p[528];
  return g;
}

// ---------------- Scan: R1's gru_scan_mfma VERBATIM (proven: 565us, absmax 0.0039) --------
// FROZEN — final. Six structural attempts to beat this (R2 16-wave spill, R4 split-burst,
// R9 hybrid-serial, R11 pinned-interleave, + R3/R5-R7 asm-hazard correctness failures) all
// regressed. With barrier-locked waves the n-gate's VALU phase costs its cycles serially
// regardless of program order; R1's single-burst structure with 2 waves/SIMD already
// captures the implicit MFMA/VALU cross-wave overlap the hardware provides.
__global__ __launch_bounds__(512, 1)
void gru_scan_m1(const float* __restrict__ times_in, const float* __restrict__ W_hh,
                 const float* __restrict__ b_hh, const __fp16* __restrict__ gx,
                 float* __restrict__ out) {
  __shared__ __align__(16) __fp16 hl[2 * Hn];
  __shared__ short act[Tn];
  __shared__ int wave_cnt[8];
  __shared__ int nact_s;

  const int tid = threadIdx.x;
  const int b = blockIdx.x;
  const int lane = tid & 63;
  const int w = tid >> 6;   // wave id 0..7: owns h-dims [w*32, w*32+32)
  const int m = lane & 15;  // tile column
  const int q = lane >> 4;  // k sub-offset group
  const int d0 = w * 32 + m;

  // ---- compact active timesteps (one-time) ----
  {
    float tv = times_in[(size_t)b * Tn + tid];
    bool on = tv > 0.f;
    unsigned long long mask = __ballot(on);
    int within = __popcll(mask & ((1ull << lane) - 1ull));
    if (lane == 0) wave_cnt[w] = __popcll(mask);
    __syncthreads();
    int off = 0;
#pragma unroll
    for (int i = 0; i < 8; ++i) off += (i < w) ? wave_cnt[i] : 0;
    if (on) act[off + within] = (short)tid;
    if (tid == 0) {
      int n = 0;
#pragma unroll
      for (int i = 0; i < 8; ++i) n += wave_cnt[i];
      nact_s = n;
    }
  }

  // ---- W_hh -> register-resident B-fragments ----
  // wb[g*2+hf][kc]: lane holds W_hh[g*256 + w*32 + hf*16 + m][kc*32 + q*8 + j], j=0..7
  half8_t wb[6][8];
#pragma unroll
  for (int g = 0; g < 3; ++g)
#pragma unroll
    for (int hf = 0; hf < 2; ++hf) {
      const float* wr = W_hh + (size_t)(g * 256 + w * 32 + hf * 16 + m) * Hn;
#pragma unroll
      for (int kc = 0; kc < 8; ++kc) {
        const float4 a = *(const float4*)(wr + kc * 32 + q * 8);
        const float4 c = *(const float4*)(wr + kc * 32 + q * 8 + 4);
        uint4 u;
        u.x = cvt2(a.x, a.y);
        u.y = cvt2(a.z, a.w);
        u.z = cvt2(c.x, c.y);
        u.w = cvt2(c.z, c.w);
        wb[g * 2 + hf][kc] = __builtin_bit_cast(half8_t, u);
      }
    }
  const float bhn0 = b_hh[512 + d0];
  const float bhn1 = b_hh[512 + d0 + 16];

  hl[tid] = (__fp16)0.f;  // both ping-pong buffers
  __syncthreads();

  const int nact = nact_s;
  const unsigned short* gxs = (const unsigned short*)(gx + (size_t)b * Tn * 768) + d0;

  float h0 = 0.f, h1 = 0.f;
  int cur = 0;

  auto step = [&](G6 g) {
    // A-fragments: h broadcast into all 16 rows -> lane reads h[kc*32 + q*8 ..+8]
    // (4 distinct 16B addrs per wave, 16-lane broadcast each: conflict-free)
    const uint4* ha = (const uint4*)(hl + cur * Hn);
    uint4 afu[8];
#pragma unroll
    for (int kc = 0; kc < 8; ++kc) afu[kc] = ha[kc * 4 + q];

    f32x4 acc[6];
#pragma unroll
    for (int t = 0; t < 6; ++t) acc[t] = f32x4{0.f, 0.f, 0.f, 0.f};
#pragma unroll
    for (int kc = 0; kc < 8; ++kc) {
      half8_t a = __builtin_bit_cast(half8_t, afu[kc]);
#pragma unroll
      for (int t = 0; t < 6; ++t)
        acc[t] = __builtin_amdgcn_mfma_f32_16x16x32_f16(a, wb[t][kc], acc[t], 0, 0, 0);
    }

    // all 16 C-rows identical (A rows identical) -> reg 0 of each acc holds gh[col m]
    float r0 = sigmoid_f(h2f(g.r0) + acc[0][0]);
    float r1 = sigmoid_f(h2f(g.r1) + acc[1][0]);
    float z0 = sigmoid_f(h2f(g.z0) + acc[2][0]);
    float z1 = sigmoid_f(h2f(g.z1) + acc[3][0]);
    float n0 = tanh_f(h2f(g.n0) + r0 * (acc[4][0] + bhn0));
    float n1 = tanh_f(h2f(g.n1) + r1 * (acc[5][0] + bhn1));
    h0 = z0 * (h0 - n0) + n0;  // (1-z)*n + z*h
    h1 = z1 * (h1 - n1) + n1;

    if (q == 0) {
      hl[(cur ^ 1) * Hn + d0] = (__fp16)h0;
      hl[(cur ^ 1) * Hn + d0 + 16] = (__fp16)h1;
    }
    // raw barrier: drain LDS only (keep gx prefetch loads in flight across steps)
    asm volatile("s_waitcnt lgkmcnt(0)" ::: "memory");
    __builtin_amdgcn_s_barrier();
    __builtin_amdgcn_sched_barrier(0);
    cur ^= 1;
  };

  if (nact > 0) {
    G6 ga = load_gx(gxs + (size_t)act[0] * 768);
    G6 gb = load_gx(gxs + (size_t)act[(nact > 1) ? 1 : 0] * 768);
    int i = 0;
#pragma unroll 1
    for (; i + 2 <= nact; i += 2) {
      const int iA = (i + 2 < nact) ? i + 2 : nact - 1;
      const int iB = (i + 3 < nact) ? i + 3 : nact - 1;
      const int tA = act[iA];
      const int tB = act[iB];
      step(ga);
      ga = load_gx(gxs + (size_t)tA * 768);  // consumed 2 steps from now
      step(gb);
      gb = load_gx(gxs + (size_t)tB * 768);
    }
    if (i < nact) step(ga);
  }

  if (q == 0) {
    out[(size_t)b * Hn + d0] = h0;
    out[(size_t)b * Hn + d0 + 16] = h1;
  }
}

// ---------------- Fallback (R3): in-kernel phase A, used only if ws too small -------------
template <bool USE_WS>
static __device__ __forceinline__ void phaseA_pass(int col, const unsigned int* __restrict__ w16,
                                                   const float* __restrict__ W_ih,
                                                   const unsigned int* x_lds, float* a) {
  const uint4* wp = (const uint4*)(w16) + (size_t)col * (WU / 4);
  const float* wf = W_ih + (size_t)col * INn;
#pragma unroll 2
  for (int kp = 0; kp < 8; ++kp) {
    uint4 wa, wb;
    if constexpr (USE_WS) {
      wa = wp[2 * kp];
      wb = wp[2 * kp + 1];
    } else {
      const float* f = wf + 16 * kp;
      wa.x = cvt2(f[0], f[1]);   wa.y = cvt2(f[2], f[3]);
      wa.z = cvt2(f[4], f[5]);   wa.w = cvt2(f[6], f[7]);
      wb.x = cvt2(f[8], f[9]);   wb.y = cvt2(f[10], f[11]);
      wb.z = cvt2(f[12], f[13]); wb.w = cvt2(f[14], f[15]);
    }
#pragma unroll
    for (int t = 0; t < Cc; ++t) {
      const uint4* xp = (const uint4*)&x_lds[t * WU + kp * 8];
      uint4 xa = xp[0], xb = xp[1];
      a[t] = dot2(wa.x, xa.x, a[t]);
      a[t] = dot2(wa.y, xa.y, a[t]);
      a[t] = dot2(wa.z, xa.z, a[t]);
      a[t] = dot2(wa.w, xa.w, a[t]);
      a[t] = dot2(wb.x, xb.x, a[t]);
      a[t] = dot2(wb.y, xb.y, a[t]);
      a[t] = dot2(wb.z, xb.z, a[t]);
      a[t] = dot2(wb.w, xb.w, a[t]);
    }
  }
  uint4 wt;
  if constexpr (USE_WS) {
    wt = wp[16];
  } else {
    wt.x = cvt2(wf[128], 0.f); wt.y = 0u; wt.z = 0u; wt.w = 0u;
  }
#pragma unroll
  for (int t = 0; t < Cc; ++t) {
    uint4 xt = *(const uint4*)&x_lds[t * WU + 64];
    a[t] = dot2(wt.x, xt.x, a[t]);
    a[t] = dot2(wt.y, xt.y, a[t]);
  }
}

template <bool USE_WS>
__global__ __launch_bounds__(512, 2)
void gru_scan_fb(const float* __restrict__ times_in, const float* __restrict__ data_in,
                 const float* __restrict__ mask_in, const unsigned int* __restrict__ w16,
                 const float* __restrict__ W_ih, const float* __restrict__ W_hh,
                 const float* __restrict__ b_ih, const float* __restrict__ b_hh,
                 float* __restrict__ out) {
  __shared__ __align__(16) float gx_lds[Cc * 768];
  __shared__ __align__(16) unsigned int x_lds[Cc * WU];
  __shared__ __align__(16) __fp16 h_buf[2 * Hn];
  __shared__ __align__(16) float t_lds[Tn];

  const int tid = threadIdx.x;
  const int b = blockIdx.x;
  const int jg = tid >> 1;
  const int ks = tid & 1;

  t_lds[tid] = times_in[(size_t)b * Tn + tid];

  unsigned int whr[64], whz[64], whn[64];
  {
    const float* w0 = W_hh + (size_t)jg * Hn + ks * 128;
    const float* w1 = W_hh + (size_t)(jg + 256) * Hn + ks * 128;
    const float* w2 = W_hh + (size_t)(jg + 512) * Hn + ks * 128;
#pragma unroll
    for (int c = 0; c < 64; ++c) {
      whr[c] = cvt2(w0[2 * c], w0[2 * c + 1]);
      whz[c] = cvt2(w1[2 * c], w1[2 * c + 1]);
      whn[c] = cvt2(w2[2 * c], w2[2 * c + 1]);
    }
  }
  const float brh = b_hh[jg];
  const float bzh = b_hh[jg + 256];
  const float bhn = b_hh[jg + 512];
  const float bi1 = b_ih[tid];
  const float bi2 = (tid < 256) ? b_ih[512 + tid] : 0.f;

  h_buf[tid] = (__fp16)0.f;
  __syncthreads();

  float hcur = 0.f;
  int cur = 0;
#pragma unroll 1
  for (int ch = 0; ch < NCH; ++ch) {
    const int t0 = ch * Cc;
    {
      int t = tid >> 6;
      int c = tid & 63;
      const float* src = (c < 32)
          ? data_in + ((size_t)b * Tn + t0 + t) * Vn + 2 * c
          : mask_in + ((size_t)b * Tn + t0 + t) * Vn + 2 * (c - 32);
      float2 v = *(const float2*)src;
      x_lds[t * WU + c] = cvt2(v.x, v.y);
      if (tid < Cc) {
        int g = t0 + tid;
        float d = (g < Tn - 1) ? (t_lds[g + 1] - t_lds[g]) : 0.f;
        uint4 tl;
        tl.x = cvt2(d, 0.f); tl.y = 0u; tl.z = 0u; tl.w = 0u;
        *(uint4*)&x_lds[tid * WU + 64] = tl;
      }
    }
    __syncthreads();
    {
      float a[Cc];
#pragma unroll
      for (int t = 0; t < Cc; ++t) a[t] = bi1;
      phaseA_pass<USE_WS>(tid, w16, W_ih, x_lds, a);
#pragma unroll
      for (int t = 0; t < Cc; ++t) gx_lds[t * 768 + tid] = a[t];
      if (tid < 256) {
#pragma unroll
        for (int t = 0; t < Cc; ++t) a[t] = bi2;
        phaseA_pass<USE_WS>(512 + tid, w16, W_ih, x_lds, a);
#pragma unroll
        for (int t = 0; t < Cc; ++t) gx_lds[t * 768 + 512 + tid] = a[t];
      }
    }
    __syncthreads();
    for (int tt = 0; tt < Cc; ++tt) {
      float sr = 0.f, sz = 0.f, shn = 0.f;
      const uint4* hb = (const uint4*)(h_buf + cur * Hn + ks * 128);
#pragma unroll
      for (int c = 0; c < 16; ++c) {
        uint4 hv = hb[c];
        sr = dot2(whr[4 * c + 0], hv.x, sr);
        sz = dot2(whz[4 * c + 0], hv.x, sz);
        shn = dot2(whn[4 * c + 0], hv.x, shn);
        sr = dot2(whr[4 * c + 1], hv.y, sr);
        sz = dot2(whz[4 * c + 1], hv.y, sz);
        shn = dot2(whn[4 * c + 1], hv.y, shn);
        sr = dot2(whr[4 * c + 2], hv.z, sr);
        sz = dot2(whz[4 * c + 2], hv.z, sz);
        shn = dot2(whn[4 * c + 2], hv.z, shn);
        sr = dot2(whr[4 * c + 3], hv.w, sr);
        sz = dot2(whz[4 * c + 3], hv.w, sz);
        shn = dot2(whn[4 * c + 3], hv.w, shn);
      }
      float gxr = gx_lds[tt * 768 + jg];
      float gxz = gx_lds[tt * 768 + 256 + jg];
      float gxn = gx_lds[tt * 768 + 512 + jg];
      sr = pair_sum(sr);
      sz = pair_sum(sz);
      shn = pair_sum(shn);
      float r = sigmoid_f(gxr + sr + brh);
      float z = sigmoid_f(gxz + sz + bzh);
      float n = tanh_f(gxn + r * (shn + bhn));
      float hN = (1.f - z) * n + z * hcur;
      hcur = (t_lds[t0 + tt] > 0.f) ? hN : hcur;
      if (ks == 0) h_buf[(cur ^ 1) * Hn + jg] = (__fp16)hcur;
      __syncthreads();
      cur ^= 1;
    }
  }
  if (ks == 0) out[(size_t)b * Hn + jg] = hcur;
}

extern "C" void kernel_launch(void* const* d_in, const int* in_sizes, int n_in,
                              void* d_out, int out_size, void* d_ws, size_t ws_size,
                              hipStream_t stream) {
  const float* times_in = (const float*)d_in[0];
  const float* data_in = (const float*)d_in[1];
  const float* mask_in = (const float*)d_in[2];
  const float* W_ih = (const float*)d_in[3];
  const float* W_hh = (const float*)d_in[4];
  const float* b_ih = (const float*)d_in[5];
  const float* b_hh = (const float*)d_in[6];
  float* out = (float*)d_out;

  unsigned int* w16 = (unsigned int*)d_ws;
  __fp16* gx = (__fp16*)((char*)d_ws + GX_OFF);

  if (ws_size >= GX_OFF + GX_BYTES) {
    hipLaunchKernelGGL(convert_wih, dim3((WSZ + 255) / 256), dim3(256), 0, stream, W_ih, w16);
    hipLaunchKernelGGL(gx_gemm, dim3(2048), dim3(256), 0, stream,
                       times_in, data_in, mask_in, w16, b_ih, b_hh, gx);
    hipLaunchKernelGGL(gru_scan_m1, dim3(Bn), dim3(512), 0, stream,
                       times_in, W_hh, b_hh, gx, out);
  } else if (ws_size >= (size_t)WSZ * 4) {
    hipLaunchKernelGGL(convert_wih, dim3((WSZ + 255) / 256), dim3(256), 0, stream, W_ih, w16);
    hipLaunchKernelGGL((gru_scan_fb<true>), dim3(Bn), dim3(512), 0, stream,
                       times_in, data_in, mask_in, w16, W_ih, W_hh, b_ih, b_hh, out);
  } else {
    hipLaunchKernelGGL((gru_scan_fb<false>), dim3(Bn), dim3(512), 0, stream,
                       times_in, data_in, mask_in, (const unsigned int*)nullptr, W_ih, W_hh,
                       b_ih, b_hh, out);
  }
}